// Round 1
// baseline (624.606 us; speedup 1.0000x reference)
//
#include <hip/hip_runtime.h>
#include <hip/hip_bf16.h>

// ---------------------------------------------------------------------------
// Problem: ASL RNN. Key insights:
//  * hidden recurrence h = h@Wt + b never reads i2h  ->  only frame T-1's
//    conv/fc pipeline matters (512 samples instead of 16384).
//  * h_32 = h_0 (G^T)^32 + b * sum_i (G^T)^i  -> compute by 5 squarings.
// Outputs: d_out[0:5120] = relu((i2h_31 + h_32) @ out_w^T + out_b)  (512x10)
//          d_out[5120:261120] = h_32                                 (512x500)
// ---------------------------------------------------------------------------

#define GBM 32
#define GBN 32
#define GBK 32

// C[m][n] = sum_k A[m*lda+k] * B[n*ldb+k] + bias[n], optional relu.
__global__ __launch_bounds__(256) void gemm_abt(
    const float* __restrict__ A, const float* __restrict__ B,
    const float* __restrict__ bias, float* __restrict__ C,
    int M, int N, int K, int lda, int ldb, int ldc, int relu)
{
    __shared__ float As[GBK][GBM + 2];
    __shared__ float Bs[GBK][GBN + 2];
    const int bm = blockIdx.x * GBM, bn = blockIdx.y * GBN;
    const int t = threadIdx.x;
    const int r = t >> 3, c4 = (t & 7) * 4;
    const int ty = t >> 4, tx = t & 15;
    float acc[2][2] = {{0.f, 0.f}, {0.f, 0.f}};

    for (int k0 = 0; k0 < K; k0 += GBK) {
        // A tile (transposed store -> K-major)
        {
            int row = bm + r;
            float4 v = make_float4(0.f, 0.f, 0.f, 0.f);
            if (row < M) {
                if (k0 + c4 + 3 < K) {
                    v = *(const float4*)(A + (size_t)row * lda + k0 + c4);
                } else {
                    float tmp[4] = {0.f, 0.f, 0.f, 0.f};
                    for (int u = 0; u < 4; u++)
                        if (k0 + c4 + u < K) tmp[u] = A[(size_t)row * lda + k0 + c4 + u];
                    v = make_float4(tmp[0], tmp[1], tmp[2], tmp[3]);
                }
            }
            As[c4 + 0][r] = v.x; As[c4 + 1][r] = v.y;
            As[c4 + 2][r] = v.z; As[c4 + 3][r] = v.w;
        }
        // B tile (B is [n][k] row-major; transposed store -> K-major)
        {
            int row = bn + r;
            float4 v = make_float4(0.f, 0.f, 0.f, 0.f);
            if (row < N) {
                if (k0 + c4 + 3 < K) {
                    v = *(const float4*)(B + (size_t)row * ldb + k0 + c4);
                } else {
                    float tmp[4] = {0.f, 0.f, 0.f, 0.f};
                    for (int u = 0; u < 4; u++)
                        if (k0 + c4 + u < K) tmp[u] = B[(size_t)row * ldb + k0 + c4 + u];
                    v = make_float4(tmp[0], tmp[1], tmp[2], tmp[3]);
                }
            }
            Bs[c4 + 0][r] = v.x; Bs[c4 + 1][r] = v.y;
            Bs[c4 + 2][r] = v.z; Bs[c4 + 3][r] = v.w;
        }
        __syncthreads();
#pragma unroll
        for (int kk = 0; kk < GBK; kk++) {
            float a0 = As[kk][ty * 2], a1 = As[kk][ty * 2 + 1];
            float b0 = Bs[kk][tx * 2], b1 = Bs[kk][tx * 2 + 1];
            acc[0][0] += a0 * b0; acc[0][1] += a0 * b1;
            acc[1][0] += a1 * b0; acc[1][1] += a1 * b1;
        }
        __syncthreads();
    }
#pragma unroll
    for (int i = 0; i < 2; i++)
#pragma unroll
        for (int j = 0; j < 2; j++) {
            int m = bm + ty * 2 + i, n = bn + tx * 2 + j;
            if (m < M && n < N) {
                float v = acc[i][j] + (bias ? bias[n] : 0.f);
                if (relu) v = fmaxf(v, 0.f);
                C[(size_t)m * ldc + n] = v;
            }
        }
}

// C[i][j] = sum_k A[i*lda+k] * B[k*ldb+j]   (plain A@B, used for squaring)
__global__ __launch_bounds__(256) void gemm_ab(
    const float* __restrict__ A, const float* __restrict__ B,
    float* __restrict__ C, int M, int N, int K, int lda, int ldb, int ldc)
{
    __shared__ float As[GBK][GBM + 2];
    __shared__ float Bs[GBK][GBN + 2];
    const int bm = blockIdx.x * GBM, bn = blockIdx.y * GBN;
    const int t = threadIdx.x;
    const int r = t >> 3, c4 = (t & 7) * 4;
    const int ty = t >> 4, tx = t & 15;
    float acc[2][2] = {{0.f, 0.f}, {0.f, 0.f}};

    for (int k0 = 0; k0 < K; k0 += GBK) {
        {   // A tile rows=m, cols=k  (transpose store)
            int row = bm + r;
            float4 v = make_float4(0.f, 0.f, 0.f, 0.f);
            if (row < M) {
                if (k0 + c4 + 3 < K) {
                    v = *(const float4*)(A + (size_t)row * lda + k0 + c4);
                } else {
                    float tmp[4] = {0.f, 0.f, 0.f, 0.f};
                    for (int u = 0; u < 4; u++)
                        if (k0 + c4 + u < K) tmp[u] = A[(size_t)row * lda + k0 + c4 + u];
                    v = make_float4(tmp[0], tmp[1], tmp[2], tmp[3]);
                }
            }
            As[c4 + 0][r] = v.x; As[c4 + 1][r] = v.y;
            As[c4 + 2][r] = v.z; As[c4 + 3][r] = v.w;
        }
        {   // B tile rows=k, cols=n  (direct store, K-major already)
            int row = k0 + r;
            float4 v = make_float4(0.f, 0.f, 0.f, 0.f);
            if (row < K) {
                if (bn + c4 + 3 < N) {
                    v = *(const float4*)(B + (size_t)row * ldb + bn + c4);
                } else {
                    float tmp[4] = {0.f, 0.f, 0.f, 0.f};
                    for (int u = 0; u < 4; u++)
                        if (bn + c4 + u < N) tmp[u] = B[(size_t)row * ldb + bn + c4 + u];
                    v = make_float4(tmp[0], tmp[1], tmp[2], tmp[3]);
                }
            }
            Bs[r][c4 + 0] = v.x; Bs[r][c4 + 1] = v.y;
            Bs[r][c4 + 2] = v.z; Bs[r][c4 + 3] = v.w;
        }
        __syncthreads();
#pragma unroll
        for (int kk = 0; kk < GBK; kk++) {
            float a0 = As[kk][ty * 2], a1 = As[kk][ty * 2 + 1];
            float b0 = Bs[kk][tx * 2], b1 = Bs[kk][tx * 2 + 1];
            acc[0][0] += a0 * b0; acc[0][1] += a0 * b1;
            acc[1][0] += a1 * b0; acc[1][1] += a1 * b1;
        }
        __syncthreads();
    }
#pragma unroll
    for (int i = 0; i < 2; i++)
#pragma unroll
        for (int j = 0; j < 2; j++) {
            int m = bm + ty * 2 + i, n = bn + tx * 2 + j;
            if (m < M && n < N) C[(size_t)m * ldc + n] = acc[i][j];
        }
}

// Per-sample hand conv (2->16, k=2) + relu + maxpool(2) for both hands.
// hand points at frame 31: (512, 84). Output hpL/hpR: (512, 304).
__global__ __launch_bounds__(128) void hand_conv(
    const float* __restrict__ hand,
    const float* __restrict__ lcw, const float* __restrict__ lcb,
    const float* __restrict__ rcw, const float* __restrict__ rcb,
    float* __restrict__ hpL, float* __restrict__ hpR)
{
    const int b = blockIdx.x;
    __shared__ float x[84];
    __shared__ float cw[2][64];
    __shared__ float cb[2][16];
    const int t = threadIdx.x;
    if (t < 84) x[t] = hand[(size_t)b * 84 + t];
    if (t < 64) { cw[0][t] = lcw[t]; cw[1][t] = rcw[t]; }
    if (t < 16) { cb[0][t] = lcb[t]; cb[1][t] = rcb[t]; }
    __syncthreads();
    for (int idx = t; idx < 608; idx += 128) {
        int hi = idx / 304, rem = idx % 304;
        int o = rem / 19, p = rem % 19;
        int off = hi * 42;
        const float* w = cw[hi];
        float w00 = w[o * 4], w01 = w[o * 4 + 1], w10 = w[o * 4 + 2], w11 = w[o * 4 + 3];
        float bs = cb[hi][o];
        // conv(q) = w00*x[2q] + w01*x[2q+2] + w10*x[2q+1] + w11*x[2q+3] + bias
        float c0 = w00 * x[off + 2 * p] + w01 * x[off + 2 * p + 2] +
                   w10 * x[off + 2 * p + 1] + w11 * x[off + 2 * p + 3] + bs;
        float c1 = w00 * x[off + 2 * p + 2] + w01 * x[off + 2 * p + 4] +
                   w10 * x[off + 2 * p + 3] + w11 * x[off + 2 * p + 5] + bs;
        float v = fmaxf(fmaxf(c0, c1), 0.f);
        (hi ? hpR : hpL)[(size_t)b * 304 + rem] = v;
    }
}

// conv2 (2->32, k=2) + relu + maxpool(3) -> feat (512, 9504)
__global__ __launch_bounds__(256) void conv2_feat(
    const float* __restrict__ both, const float* __restrict__ w2g,
    const float* __restrict__ b2g, float* __restrict__ feat)
{
    const int b = blockIdx.x;
    __shared__ float s[600];
    __shared__ float c2[32 * 299];
    __shared__ float w2[128];
    __shared__ float b2[32];
    const int t = threadIdx.x;
    for (int i = t; i < 600; i += 256) s[i] = both[(size_t)b * 600 + i];
    if (t < 128) w2[t] = w2g[t];
    if (t < 32) b2[t] = b2g[t];
    __syncthreads();
    for (int idx = t; idx < 32 * 299; idx += 256) {
        int o = idx / 299, q = idx % 299;
        float v = w2[o * 4] * s[q] + w2[o * 4 + 1] * s[q + 1] +
                  w2[o * 4 + 2] * s[300 + q] + w2[o * 4 + 3] * s[300 + q + 1] + b2[o];
        c2[idx] = fmaxf(v, 0.f);
    }
    __syncthreads();
    for (int idx = t; idx < 9504; idx += 256) {
        int o = idx / 297, p = idx % 297;
        float v = fmaxf(fmaxf(c2[o * 299 + p], c2[o * 299 + p + 1]), c2[o * 299 + p + 2]);
        feat[(size_t)b * 9504 + idx] = v;
    }
}

// unew[j] = sum_a u[a] * P[j*500+a] + u[j]    (u_{2k} = u_k (P_k)^T + u_k)
__global__ __launch_bounds__(256) void vec_update(
    const float* __restrict__ u, const float* __restrict__ P,
    float* __restrict__ unew)
{
    __shared__ float us[500];
    const int t = threadIdx.x;
    const int j = blockIdx.x * 256 + t;
    for (int i = t; i < 500; i += 256) us[i] = u[i];
    __syncthreads();
    if (j < 500) {
        float acc = us[j];
        const float* row = P + (size_t)j * 500;
        for (int a = 0; a < 500; a++) acc += us[a] * row[a];
        unew[j] = acc;
    }
}

// out[b][o] = relu( sum_j (i2h[b][j]+h[b][j]) * ow[o][j] + ob[o] )
__global__ __launch_bounds__(64) void out_kernel(
    const float* __restrict__ i2h, const float* __restrict__ h,
    const float* __restrict__ ow, const float* __restrict__ ob,
    float* __restrict__ out)
{
    const int b = blockIdx.x, lane = threadIdx.x;
    float s[8];
#pragma unroll
    for (int r = 0; r < 8; r++) {
        int j = lane + r * 64;
        s[r] = (j < 500) ? (i2h[(size_t)b * 500 + j] + h[(size_t)b * 500 + j]) : 0.f;
    }
    for (int o = 0; o < 10; o++) {
        float acc = 0.f;
#pragma unroll
        for (int r = 0; r < 8; r++) {
            int j = lane + r * 64;
            if (j < 500) acc += s[r] * ow[o * 500 + j];
        }
        for (int off = 32; off; off >>= 1) acc += __shfl_down(acc, off);
        if (lane == 0) out[(size_t)b * 10 + o] = fmaxf(acc + ob[o], 0.f);
    }
}

extern "C" void kernel_launch(void* const* d_in, const int* in_sizes, int n_in,
                              void* d_out, int out_size, void* d_ws, size_t ws_size,
                              hipStream_t stream) {
    const float* hand   = (const float*)d_in[0];   // (32,512,84)
    const float* hidden = (const float*)d_in[1];   // (512,500)
    const float* lcw = (const float*)d_in[2];
    const float* lcb = (const float*)d_in[3];
    const float* lfw = (const float*)d_in[4];      // (300,304)
    const float* lfb = (const float*)d_in[5];
    const float* rcw = (const float*)d_in[6];
    const float* rcb = (const float*)d_in[7];
    const float* rfw = (const float*)d_in[8];
    const float* rfb = (const float*)d_in[9];
    const float* w2  = (const float*)d_in[10];     // (32,2,2)
    const float* b2  = (const float*)d_in[11];
    const float* l2w = (const float*)d_in[12];     // (500,9504)
    const float* l2b = (const float*)d_in[13];
    const float* hw  = (const float*)d_in[14];     // (500,500) = G
    const float* hb  = (const float*)d_in[15];
    const float* ow  = (const float*)d_in[16];     // (10,500)
    const float* ob  = (const float*)d_in[17];

    float* ws   = (float*)d_ws;
    float* feat = ws;                              // 512*9504
    float* hpL  = feat + (size_t)512 * 9504;       // 512*304
    float* hpR  = hpL + (size_t)512 * 304;         // 512*304
    float* both = hpR + (size_t)512 * 304;         // 512*600
    float* i2h  = both + (size_t)512 * 600;        // 512*500
    float* Pa   = i2h + (size_t)512 * 500;         // 500*500
    float* Pb   = Pa + 250000;                     // 500*500
    float* ua   = Pb + 250000;                     // 500
    float* ub   = ua + 500;                        // 500

    float* out  = (float*)d_out;                   // 512*10
    float* hout = out + 5120;                      // 512*500 (2nd output)

    // frame 31 hand branches
    hand_conv<<<512, 128, 0, stream>>>(hand + (size_t)31 * 512 * 84,
                                       lcw, lcb, rcw, rcb, hpL, hpR);
    // fc per hand -> both[b][c][300]
    gemm_abt<<<dim3(16, 10), 256, 0, stream>>>(hpL, lfw, lfb, both,
                                               512, 300, 304, 304, 304, 600, 1);
    gemm_abt<<<dim3(16, 10), 256, 0, stream>>>(hpR, rfw, rfb, both + 300,
                                               512, 300, 304, 304, 304, 600, 1);
    // conv2 + pool3 -> feat
    conv2_feat<<<512, 256, 0, stream>>>(both, w2, b2, feat);
    // i2h = feat @ l2w^T + l2b
    gemm_abt<<<dim3(16, 16), 256, 0, stream>>>(feat, l2w, l2b, i2h,
                                               512, 500, 9504, 9504, 9504, 500, 0);
    // 5 squarings: P_{2k} = P_k @ P_k ; u_{2k} = u_k P_k^T + u_k
    const float* Pcur = hw;
    const float* ucur = hb;
    float* Pn[5] = {Pa, Pb, Pa, Pb, Pa};
    float* un[5] = {ua, ub, ua, ub, ua};
    for (int i = 0; i < 5; i++) {
        gemm_ab<<<dim3(16, 16), 256, 0, stream>>>(Pcur, Pcur, Pn[i],
                                                  500, 500, 500, 500, 500, 500);
        vec_update<<<2, 256, 0, stream>>>(ucur, Pcur, un[i]);
        Pcur = Pn[i];
        ucur = un[i];
    }
    // h_32 = hidden @ P32^T + u32  -> directly into d_out (2nd output)
    gemm_abt<<<dim3(16, 16), 256, 0, stream>>>(hidden, Pcur, ucur, hout,
                                               512, 500, 500, 500, 500, 500, 0);
    // out = relu((i2h + h) @ ow^T + ob)
    out_kernel<<<512, 64, 0, stream>>>(i2h, hout, ow, ob, out);
}

// Round 2
// 303.889 us; speedup vs baseline: 2.0554x; 2.0554x over previous
//
#include <hip/hip_runtime.h>
#include <hip/hip_bf16.h>

// ---------------------------------------------------------------------------
// ASL RNN. Structural insights (verified round 1):
//  * hidden recurrence never reads i2h -> only frame T-1 (512 samples) needs
//    the conv/fc pipeline.
//  * h_32 = hidden*(W^T... stored form) via 5 matrix squarings + vector recurrence.
// Round 2: l2 GEMM (512x500x9504) in bf16 MFMA (16x16x32) with split-K;
//          squarings/fc/h in 4x4-microtile fp32; parallel vec_update.
// ---------------------------------------------------------------------------

typedef __attribute__((ext_vector_type(8))) unsigned short us8;
typedef __attribute__((ext_vector_type(8))) __bf16 bf8v;
typedef __attribute__((ext_vector_type(4))) float f4v;

static __device__ __forceinline__ unsigned short f2bf(float x) {
    __hip_bfloat16 h = __float2bfloat16(x);
    return *reinterpret_cast<unsigned short*>(&h);
}

static __device__ __forceinline__ void gload16(const void* g, void* s) {
    typedef __attribute__((address_space(1))) const void gv_t;
    typedef __attribute__((address_space(3))) void sv_t;
    __builtin_amdgcn_global_load_lds((gv_t*)g, (sv_t*)s, 16, 0, 0);
}

static __device__ __forceinline__ float4 ldg4_guard(
    const float* __restrict__ p, int r, int R, int c, int C, int ld)
{
    float4 v = make_float4(0.f, 0.f, 0.f, 0.f);
    if (r < R) {
        if (c + 3 < C) {
            v = *(const float4*)(p + (size_t)r * ld + c);
        } else {
            float tmp[4] = {0.f, 0.f, 0.f, 0.f};
            for (int u = 0; u < 4; ++u)
                if (c + u < C) tmp[u] = p[(size_t)r * ld + c + u];
            v = make_float4(tmp[0], tmp[1], tmp[2], tmp[3]);
        }
    }
    return v;
}

// ---------------------------------------------------------------------------
// bf16 MFMA GEMM: Cp[z] += A(512xKp) * B(512xKp)^T over K-chunk z.
// 128x128 tile, 4 waves (each 64x64 = 4x4 frags), BK=64, global_load_lds(16B),
// XOR-8 swizzle (logical slot s at physical p = s ^ (row&7), 16B slots).
// ---------------------------------------------------------------------------
#define KSTR 9536   // padded K (bf16 elems), 149 stages of 64

__global__ __launch_bounds__(256, 1) void mfma_bt(
    const unsigned short* __restrict__ A, const unsigned short* __restrict__ B,
    float* __restrict__ Cp, int nper, int ntot)
{
    __shared__ alignas(16) unsigned short Al[2][8192];  // [buf][row*64 ush], 128 rows x 128B
    __shared__ alignas(16) unsigned short Bl[2][8192];
    const int bm = blockIdx.x * 128, bn = blockIdx.y * 128;
    const int z = blockIdx.z;
    int s0 = z * nper;
    int s1 = s0 + nper; if (s1 > ntot) s1 = ntot;
    const int ns = s1 - s0;
    const int t = threadIdx.x, w = t >> 6, l = t & 63;
    const int srow = l >> 3;                 // 0..7 row-within-8
    const int sslot = (l & 7) ^ srow;        // logical k-slot fetched by this lane
    const int wm = (w >> 1) * 64, wn = (w & 1) * 64;
    const int fr = l & 15, jj = l >> 4;      // frag row, k-subslot
    f4v acc[4][4] = {};

    const unsigned short* Ab = A + (size_t)(bm + 32 * w + srow) * KSTR + sslot * 8;
    const unsigned short* Bb = B + (size_t)(bn + 32 * w + srow) * KSTR + sslot * 8;

#define STAGE(buf, st)                                                          \
    {                                                                           \
        size_t k0 = (size_t)(s0 + (st)) * 64;                                   \
        _Pragma("unroll")                                                       \
        for (int q = 0; q < 4; ++q) {                                           \
            gload16(Ab + (size_t)(8 * q) * KSTR + k0,                           \
                    &Al[buf][(32 * w + 8 * q) * 64]);                           \
            gload16(Bb + (size_t)(8 * q) * KSTR + k0,                           \
                    &Bl[buf][(32 * w + 8 * q) * 64]);                           \
        }                                                                       \
    }

#define COMPUTE(buf)                                                            \
    {                                                                           \
        _Pragma("unroll")                                                       \
        for (int kk = 0; kk < 2; ++kk) {                                        \
            bf8v af[4], bf[4];                                                  \
            _Pragma("unroll")                                                   \
            for (int f = 0; f < 4; ++f) {                                       \
                int rA = wm + f * 16 + fr;                                      \
                int pA = (jj + 4 * kk) ^ (rA & 7);                              \
                af[f] = __builtin_bit_cast(bf8v,                                \
                        *(const us8*)&Al[buf][rA * 64 + pA * 8]);               \
                int rB = wn + f * 16 + fr;                                      \
                int pB = (jj + 4 * kk) ^ (rB & 7);                              \
                bf[f] = __builtin_bit_cast(bf8v,                                \
                        *(const us8*)&Bl[buf][rB * 64 + pB * 8]);               \
            }                                                                   \
            _Pragma("unroll")                                                   \
            for (int fi = 0; fi < 4; ++fi)                                      \
                _Pragma("unroll")                                               \
                for (int fj = 0; fj < 4; ++fj)                                  \
                    acc[fi][fj] = __builtin_amdgcn_mfma_f32_16x16x32_bf16(      \
                        af[fi], bf[fj], acc[fi][fj], 0, 0, 0);                  \
        }                                                                       \
    }

    STAGE(0, 0);
    __syncthreads();
    int cur = 0;
    for (int st = 0; st < ns; ++st) {
        if (st + 1 < ns) STAGE(cur ^ 1, st + 1);
        COMPUTE(cur);
        __syncthreads();
        cur ^= 1;
    }

    float* Cz = Cp + (size_t)z * 262144;
#pragma unroll
    for (int fi = 0; fi < 4; ++fi)
#pragma unroll
        for (int fj = 0; fj < 4; ++fj)
#pragma unroll
            for (int r = 0; r < 4; ++r) {
                int m = bm + wm + fi * 16 + jj * 4 + r;
                int n = bn + wn + fj * 16 + fr;
                Cz[(size_t)m * 512 + n] = acc[fi][fj][r];
            }
#undef STAGE
#undef COMPUTE
}

// i2h[m][n] = sum_z Cp[z][m][n] + bias[n]
__global__ __launch_bounds__(256) void reduce_i2h(
    const float* __restrict__ Cp, const float* __restrict__ bias,
    float* __restrict__ i2h)
{
    int idx = blockIdx.x * 256 + threadIdx.x;
    if (idx >= 512 * 500) return;
    int m = idx / 500, n = idx - m * 500;
    float s = bias[n];
#pragma unroll
    for (int zz = 0; zz < 4; ++zz) s += Cp[(size_t)zz * 262144 + (size_t)m * 512 + n];
    i2h[idx] = s;
}

// ---------------------------------------------------------------------------
// fp32 GEMM, 64x64 tile, 4x4 microtile.  bt: C = A*B^T (+bias)(+relu)
// ---------------------------------------------------------------------------
__global__ __launch_bounds__(256) void gemm32_bt(
    const float* __restrict__ A, const float* __restrict__ B,
    const float* __restrict__ bias, float* __restrict__ C,
    int M, int N, int K, int lda, int ldb, int ldc, int relu)
{
    __shared__ alignas(16) float As[16][68];
    __shared__ alignas(16) float Bs[16][68];
    const int t = threadIdx.x;
    const int bm = blockIdx.x * 64, bn = blockIdx.y * 64;
    const int lr = t >> 2, kq = (t & 3) * 4;
    const int ty = t >> 4, tx = t & 15;
    float acc[4][4] = {};
    float4 a0 = ldg4_guard(A, bm + lr, M, kq, K, lda);
    float4 b0 = ldg4_guard(B, bn + lr, N, kq, K, ldb);
    for (int k0 = 0; k0 < K; k0 += 16) {
        __syncthreads();
        As[kq + 0][lr] = a0.x; As[kq + 1][lr] = a0.y;
        As[kq + 2][lr] = a0.z; As[kq + 3][lr] = a0.w;
        Bs[kq + 0][lr] = b0.x; Bs[kq + 1][lr] = b0.y;
        Bs[kq + 2][lr] = b0.z; Bs[kq + 3][lr] = b0.w;
        __syncthreads();
        if (k0 + 16 < K) {
            a0 = ldg4_guard(A, bm + lr, M, k0 + 16 + kq, K, lda);
            b0 = ldg4_guard(B, bn + lr, N, k0 + 16 + kq, K, ldb);
        }
#pragma unroll
        for (int k = 0; k < 16; ++k) {
            float4 av = *(const float4*)&As[k][ty * 4];
            float4 bv = *(const float4*)&Bs[k][tx * 4];
            float aa[4] = {av.x, av.y, av.z, av.w};
            float bb[4] = {bv.x, bv.y, bv.z, bv.w};
#pragma unroll
            for (int i = 0; i < 4; ++i)
#pragma unroll
                for (int j = 0; j < 4; ++j)
                    acc[i][j] = fmaf(aa[i], bb[j], acc[i][j]);
        }
    }
#pragma unroll
    for (int i = 0; i < 4; ++i) {
        int m = bm + ty * 4 + i;
        if (m >= M) continue;
#pragma unroll
        for (int j = 0; j < 4; ++j) {
            int n = bn + tx * 4 + j;
            if (n >= N) continue;
            float v = acc[i][j] + (bias ? bias[n] : 0.f);
            if (relu) v = fmaxf(v, 0.f);
            C[(size_t)m * ldc + n] = v;
        }
    }
}

// ab: C = A*B (plain), for matrix squaring.
__global__ __launch_bounds__(256) void gemm32_ab(
    const float* __restrict__ A, const float* __restrict__ B,
    float* __restrict__ C, int M, int N, int K, int lda, int ldb, int ldc)
{
    __shared__ alignas(16) float As[16][68];
    __shared__ alignas(16) float Bs[16][68];
    const int t = threadIdx.x;
    const int bm = blockIdx.x * 64, bn = blockIdx.y * 64;
    const int lr = t >> 2, kq = (t & 3) * 4;
    const int kr = t >> 4, cq = (t & 15) * 4;
    const int ty = t >> 4, tx = t & 15;
    float acc[4][4] = {};
    float4 a0 = ldg4_guard(A, bm + lr, M, kq, K, lda);
    float4 b0 = ldg4_guard(B, kr, K, bn + cq, N, ldb);
    for (int k0 = 0; k0 < K; k0 += 16) {
        __syncthreads();
        As[kq + 0][lr] = a0.x; As[kq + 1][lr] = a0.y;
        As[kq + 2][lr] = a0.z; As[kq + 3][lr] = a0.w;
        *(float4*)&Bs[kr][cq] = b0;
        __syncthreads();
        if (k0 + 16 < K) {
            a0 = ldg4_guard(A, bm + lr, M, k0 + 16 + kq, K, lda);
            b0 = ldg4_guard(B, k0 + 16 + kr, K, bn + cq, N, ldb);
        }
#pragma unroll
        for (int k = 0; k < 16; ++k) {
            float4 av = *(const float4*)&As[k][ty * 4];
            float4 bv = *(const float4*)&Bs[k][tx * 4];
            float aa[4] = {av.x, av.y, av.z, av.w};
            float bb[4] = {bv.x, bv.y, bv.z, bv.w};
#pragma unroll
            for (int i = 0; i < 4; ++i)
#pragma unroll
                for (int j = 0; j < 4; ++j)
                    acc[i][j] = fmaf(aa[i], bb[j], acc[i][j]);
        }
    }
#pragma unroll
    for (int i = 0; i < 4; ++i) {
        int m = bm + ty * 4 + i;
        if (m >= M) continue;
#pragma unroll
        for (int j = 0; j < 4; ++j) {
            int n = bn + tx * 4 + j;
            if (n >= N) continue;
            C[(size_t)m * ldc + n] = acc[i][j];
        }
    }
}

// ---------------------------------------------------------------------------
// Small fused kernels
// ---------------------------------------------------------------------------
__global__ __launch_bounds__(128) void hand_conv(
    const float* __restrict__ hand,
    const float* __restrict__ lcw, const float* __restrict__ lcb,
    const float* __restrict__ rcw, const float* __restrict__ rcb,
    float* __restrict__ hpL, float* __restrict__ hpR)
{
    const int b = blockIdx.x;
    __shared__ float x[84];
    __shared__ float cw[2][64];
    __shared__ float cb[2][16];
    const int t = threadIdx.x;
    if (t < 84) x[t] = hand[(size_t)b * 84 + t];
    if (t < 64) { cw[0][t] = lcw[t]; cw[1][t] = rcw[t]; }
    if (t < 16) { cb[0][t] = lcb[t]; cb[1][t] = rcb[t]; }
    __syncthreads();
    for (int idx = t; idx < 608; idx += 128) {
        int hi = idx / 304, rem = idx % 304;
        int o = rem / 19, p = rem % 19;
        int off = hi * 42;
        const float* w = cw[hi];
        float w00 = w[o * 4], w01 = w[o * 4 + 1], w10 = w[o * 4 + 2], w11 = w[o * 4 + 3];
        float bs = cb[hi][o];
        float c0 = w00 * x[off + 2 * p] + w01 * x[off + 2 * p + 2] +
                   w10 * x[off + 2 * p + 1] + w11 * x[off + 2 * p + 3] + bs;
        float c1 = w00 * x[off + 2 * p + 2] + w01 * x[off + 2 * p + 4] +
                   w10 * x[off + 2 * p + 3] + w11 * x[off + 2 * p + 5] + bs;
        float v = fmaxf(fmaxf(c0, c1), 0.f);
        (hi ? hpR : hpL)[(size_t)b * 304 + rem] = v;
    }
}

// conv2 + relu + maxpool(3) -> bf16 feat (512 x 9536, tail zeroed)
__global__ __launch_bounds__(256) void conv2_feat(
    const float* __restrict__ both, const float* __restrict__ w2g,
    const float* __restrict__ b2g, unsigned short* __restrict__ feat)
{
    const int b = blockIdx.x;
    __shared__ float s[600];
    __shared__ float c2[32 * 299];
    __shared__ float w2[128];
    __shared__ float b2[32];
    const int t = threadIdx.x;
    for (int i = t; i < 600; i += 256) s[i] = both[(size_t)b * 600 + i];
    if (t < 128) w2[t] = w2g[t];
    if (t < 32) b2[t] = b2g[t];
    __syncthreads();
    for (int idx = t; idx < 32 * 299; idx += 256) {
        int o = idx / 299, q = idx % 299;
        float v = w2[o * 4] * s[q] + w2[o * 4 + 1] * s[q + 1] +
                  w2[o * 4 + 2] * s[300 + q] + w2[o * 4 + 3] * s[300 + q + 1] + b2[o];
        c2[idx] = fmaxf(v, 0.f);
    }
    __syncthreads();
    for (int idx = t; idx < 9536; idx += 256) {
        unsigned short ov = 0;
        if (idx < 9504) {
            int o = idx / 297, p = idx % 297;
            float v = fmaxf(fmaxf(c2[o * 299 + p], c2[o * 299 + p + 1]),
                            c2[o * 299 + p + 2]);
            ov = f2bf(v);
        }
        feat[(size_t)b * 9536 + idx] = ov;
    }
}

// l2w (500x9504 f32) -> padded bf16 (512x9536)
__global__ __launch_bounds__(256) void cvt_w(
    const float* __restrict__ W, unsigned short* __restrict__ Wb)
{
    int idx = blockIdx.x * 256 + threadIdx.x;   // one per 8 elems
    int row = idx / 1192;
    int k8 = (idx - row * 1192) * 8;
    if (row >= 512) return;
    us8 o = (us8)0;
    if (row < 500 && k8 < 9504) {
        const float* p = W + (size_t)row * 9504 + k8;
        float4 v0 = *(const float4*)p;
        float4 v1 = *(const float4*)(p + 4);
        o[0] = f2bf(v0.x); o[1] = f2bf(v0.y); o[2] = f2bf(v0.z); o[3] = f2bf(v0.w);
        o[4] = f2bf(v1.x); o[5] = f2bf(v1.y); o[6] = f2bf(v1.z); o[7] = f2bf(v1.w);
    }
    *(us8*)(Wb + (size_t)row * 9536 + k8) = o;
}

// unew[j] = sum_a u[a]*P[j][a] + u[j]; one block per j
__global__ __launch_bounds__(256) void vec_update(
    const float* __restrict__ u, const float* __restrict__ P,
    float* __restrict__ unew)
{
    const int j = blockIdx.x;
    if (j >= 500) return;
    const float* row = P + (size_t)j * 500;
    const int t = threadIdx.x;
    float s = 0.f;
    for (int a = t; a < 500; a += 256) s += u[a] * row[a];
    __shared__ float red[4];
    for (int off = 32; off; off >>= 1) s += __shfl_down(s, off);
    if ((t & 63) == 0) red[t >> 6] = s;
    __syncthreads();
    if (t == 0) unew[j] = red[0] + red[1] + red[2] + red[3] + u[j];
}

// out[b][o] = relu( sum_j (i2h[b][j]+h[b][j]) * ow[o][j] + ob[o] )
__global__ __launch_bounds__(64) void out_kernel(
    const float* __restrict__ i2h, const float* __restrict__ h,
    const float* __restrict__ ow, const float* __restrict__ ob,
    float* __restrict__ out)
{
    const int b = blockIdx.x, lane = threadIdx.x;
    float s[8];
#pragma unroll
    for (int r = 0; r < 8; r++) {
        int j = lane + r * 64;
        s[r] = (j < 500) ? (i2h[(size_t)b * 500 + j] + h[(size_t)b * 500 + j]) : 0.f;
    }
    for (int o = 0; o < 10; o++) {
        float acc = 0.f;
#pragma unroll
        for (int r = 0; r < 8; r++) {
            int j = lane + r * 64;
            if (j < 500) acc += s[r] * ow[o * 500 + j];
        }
        for (int off = 32; off; off >>= 1) acc += __shfl_down(acc, off);
        if (lane == 0) out[(size_t)b * 10 + o] = fmaxf(acc + ob[o], 0.f);
    }
}

extern "C" void kernel_launch(void* const* d_in, const int* in_sizes, int n_in,
                              void* d_out, int out_size, void* d_ws, size_t ws_size,
                              hipStream_t stream) {
    const float* hand   = (const float*)d_in[0];
    const float* hidden = (const float*)d_in[1];
    const float* lcw = (const float*)d_in[2];
    const float* lcb = (const float*)d_in[3];
    const float* lfw = (const float*)d_in[4];
    const float* lfb = (const float*)d_in[5];
    const float* rcw = (const float*)d_in[6];
    const float* rcb = (const float*)d_in[7];
    const float* rfw = (const float*)d_in[8];
    const float* rfb = (const float*)d_in[9];
    const float* w2  = (const float*)d_in[10];
    const float* b2  = (const float*)d_in[11];
    const float* l2w = (const float*)d_in[12];
    const float* l2b = (const float*)d_in[13];
    const float* hw  = (const float*)d_in[14];
    const float* hb  = (const float*)d_in[15];
    const float* ow  = (const float*)d_in[16];
    const float* ob  = (const float*)d_in[17];

    char* wsb = (char*)d_ws;
    unsigned short* featb = (unsigned short*)wsb;                  // 9,764,864 B
    unsigned short* wbf   = (unsigned short*)(wsb + 9764864);      // 9,764,864 B
    char* uni = wsb + 19529728;          // union: {hpL,hpR,both} | Cp (4 MB)
    float* hpL  = (float*)uni;
    float* hpR  = (float*)(uni + 622592);
    float* both = (float*)(uni + 1245184);
    float* Cp   = (float*)uni;
    char* rest = uni + 4194304;
    float* i2h = (float*)rest;
    float* Pa  = (float*)(rest + 1024000);
    float* Pb  = (float*)(rest + 2024000);
    float* ua  = (float*)(rest + 3024000);
    float* ub  = (float*)(rest + 3026000);

    float* out  = (float*)d_out;
    float* hout = out + 5120;

    // 0) weight conversion (independent)
    cvt_w<<<2384, 256, 0, stream>>>(l2w, wbf);
    // 1) frame-31 hand branches
    hand_conv<<<512, 128, 0, stream>>>(hand + (size_t)31 * 512 * 84,
                                       lcw, lcb, rcw, rcb, hpL, hpR);
    // 2) per-hand fc -> both[b][c][300]
    gemm32_bt<<<dim3(8, 5), 256, 0, stream>>>(hpL, lfw, lfb, both,
                                              512, 300, 304, 304, 304, 600, 1);
    gemm32_bt<<<dim3(8, 5), 256, 0, stream>>>(hpR, rfw, rfb, both + 300,
                                              512, 300, 304, 304, 304, 600, 1);
    // 3) conv2 + pool3 -> bf16 feat
    conv2_feat<<<512, 256, 0, stream>>>(both, w2, b2, featb);
    // 4) i2h = feat @ l2w^T + l2b  (bf16 MFMA, split-K=4 over 149 stages)
    mfma_bt<<<dim3(4, 4, 4), 256, 0, stream>>>(featb, wbf, Cp, 38, 149);
    reduce_i2h<<<1000, 256, 0, stream>>>(Cp, l2b, i2h);
    // 5) 5 squarings + vector recurrence
    const float* Pcur = hw;
    const float* ucur = hb;
    float* Pn[5] = {Pa, Pb, Pa, Pb, Pa};
    float* un[5] = {ua, ub, ua, ub, ua};
    for (int i = 0; i < 5; i++) {
        gemm32_ab<<<dim3(8, 8), 256, 0, stream>>>(Pcur, Pcur, Pn[i],
                                                  500, 500, 500, 500, 500, 500);
        vec_update<<<500, 256, 0, stream>>>(ucur, Pcur, un[i]);
        Pcur = Pn[i];
        ucur = un[i];
    }
    // 6) h_32 = hidden @ P32^T + u32
    gemm32_bt<<<dim3(8, 8), 256, 0, stream>>>(hidden, Pcur, ucur, hout,
                                              512, 500, 500, 500, 500, 500, 0);
    // 7) out = relu((i2h + h) @ ow^T + ob)
    out_kernel<<<512, 64, 0, stream>>>(i2h, hout, ow, ob, out);
}

// Round 3
// 149.591 us; speedup vs baseline: 4.1754x; 2.0315x over previous
//
#include <hip/hip_runtime.h>
#include <hip/hip_bf16.h>

// ---------------------------------------------------------------------------
// ASL RNN.  Structure (verified rounds 1-2):
//  * recurrence never reads i2h -> only frame T-1 (512 samples) runs the
//    conv/fc pipeline.
//  * h_32 = hidden*(G^T)^32 + b*sum_i (G^T)^i via 5 matrix squarings.
// Round 3: parallelism. mfma GEMM: 64x64 tiles, split-K=8 (512 blocks).
//          squarings: split-K=4 (256 blocks) + fused reduce/vec_update.
//          reduce_i2h + h-partial reduce folded into final output kernel.
// ---------------------------------------------------------------------------

typedef __attribute__((ext_vector_type(8))) unsigned short us8;
typedef __attribute__((ext_vector_type(8))) __bf16 bf8v;
typedef __attribute__((ext_vector_type(4))) float f4v;

static __device__ __forceinline__ unsigned short f2bf(float x) {
    __hip_bfloat16 h = __float2bfloat16(x);
    return *reinterpret_cast<unsigned short*>(&h);
}

static __device__ __forceinline__ void gload16(const void* g, void* s) {
    typedef __attribute__((address_space(1))) const void gv_t;
    typedef __attribute__((address_space(3))) void sv_t;
    __builtin_amdgcn_global_load_lds((gv_t*)g, (sv_t*)s, 16, 0, 0);
}

static __device__ __forceinline__ float4 ldg4_guard(
    const float* __restrict__ p, int r, int R, int c, int C, int ld)
{
    float4 v = make_float4(0.f, 0.f, 0.f, 0.f);
    if (r < R) {
        if (c + 3 < C) {
            v = *(const float4*)(p + (size_t)r * ld + c);
        } else {
            float tmp[4] = {0.f, 0.f, 0.f, 0.f};
            for (int u = 0; u < 4; ++u)
                if (c + u < C) tmp[u] = p[(size_t)r * ld + c + u];
            v = make_float4(tmp[0], tmp[1], tmp[2], tmp[3]);
        }
    }
    return v;
}

// ---------------------------------------------------------------------------
// bf16 MFMA GEMM partials: Cp[z][m][n] = sum_{K-chunk z} feat[m][k]*W[n][k].
// 64x64 tile, 4 waves (each 32x32 = 2x2 frags), BK=64, global_load_lds(16B),
// XOR-8 swizzle.  grid (8,8,8) = 512 blocks, 2 blocks/CU.
// ---------------------------------------------------------------------------
#define KSTR 9536   // padded K (bf16 elems), 149 stages of 64

__global__ __launch_bounds__(256, 2) void mfma_bt(
    const unsigned short* __restrict__ A, const unsigned short* __restrict__ B,
    float* __restrict__ Cp, int nper, int ntot)
{
    __shared__ alignas(16) unsigned short Al[2][4096];  // 64 rows x 64 bf16
    __shared__ alignas(16) unsigned short Bl[2][4096];
    const int bm = blockIdx.x * 64, bn = blockIdx.y * 64;
    const int z = blockIdx.z;
    int s0 = z * nper;
    int s1 = s0 + nper; if (s1 > ntot) s1 = ntot;
    const int ns = s1 - s0;
    const int t = threadIdx.x, w = t >> 6, l = t & 63;
    const int srow = l >> 3;                 // row within 8-row group
    const int sslot = (l & 7) ^ srow;        // logical 16B k-slot for this lane
    const int wm = (w >> 1) * 32, wn = (w & 1) * 32;
    const int fr = l & 15, jj = l >> 4;
    f4v acc[2][2] = {};

    const unsigned short* Ab = A + (size_t)(bm + 16 * w + srow) * KSTR + sslot * 8;
    const unsigned short* Bb = B + (size_t)(bn + 16 * w + srow) * KSTR + sslot * 8;

#define STAGE(buf, st)                                                          \
    {                                                                           \
        size_t k0 = (size_t)(s0 + (st)) * 64;                                   \
        _Pragma("unroll")                                                       \
        for (int q = 0; q < 2; ++q) {                                           \
            gload16(Ab + (size_t)(8 * q) * KSTR + k0,                           \
                    &Al[buf][(16 * w + 8 * q) * 64]);                           \
            gload16(Bb + (size_t)(8 * q) * KSTR + k0,                           \
                    &Bl[buf][(16 * w + 8 * q) * 64]);                           \
        }                                                                       \
    }

#define COMPUTE(buf)                                                            \
    {                                                                           \
        _Pragma("unroll")                                                       \
        for (int kk = 0; kk < 2; ++kk) {                                        \
            bf8v af[2], bf[2];                                                  \
            _Pragma("unroll")                                                   \
            for (int f = 0; f < 2; ++f) {                                       \
                int rA = wm + f * 16 + fr;                                      \
                int pA = (jj + 4 * kk) ^ (rA & 7);                              \
                af[f] = __builtin_bit_cast(bf8v,                                \
                        *(const us8*)&Al[buf][rA * 64 + pA * 8]);               \
                int rB = wn + f * 16 + fr;                                      \
                int pB = (jj + 4 * kk) ^ (rB & 7);                              \
                bf[f] = __builtin_bit_cast(bf8v,                                \
                        *(const us8*)&Bl[buf][rB * 64 + pB * 8]);               \
            }                                                                   \
            _Pragma("unroll")                                                   \
            for (int fi = 0; fi < 2; ++fi)                                      \
                _Pragma("unroll")                                               \
                for (int fj = 0; fj < 2; ++fj)                                  \
                    acc[fi][fj] = __builtin_amdgcn_mfma_f32_16x16x32_bf16(      \
                        af[fi], bf[fj], acc[fi][fj], 0, 0, 0);                  \
        }                                                                       \
    }

    STAGE(0, 0);
    __syncthreads();
    int cur = 0;
    for (int st = 0; st < ns; ++st) {
        if (st + 1 < ns) STAGE(cur ^ 1, st + 1);
        COMPUTE(cur);
        __syncthreads();
        cur ^= 1;
    }

    float* Cz = Cp + (size_t)z * 262144;
#pragma unroll
    for (int fi = 0; fi < 2; ++fi)
#pragma unroll
        for (int fj = 0; fj < 2; ++fj)
#pragma unroll
            for (int r = 0; r < 4; ++r) {
                int m = bm + wm + fi * 16 + jj * 4 + r;
                int n = bn + wn + fj * 16 + fr;
                Cz[(size_t)m * 512 + n] = acc[fi][fj][r];
            }
#undef STAGE
#undef COMPUTE
}

// ---------------------------------------------------------------------------
// fp32 64x64-tile 4x4-microtile GEMM variants
// ---------------------------------------------------------------------------

// both hand FCs in one launch: z = hand.  C=A*B^T+bias, relu.  K=304 exact.
__global__ __launch_bounds__(256) void fc_gemm(
    const float* __restrict__ hpL, const float* __restrict__ hpR,
    const float* __restrict__ lfw, const float* __restrict__ rfw,
    const float* __restrict__ lfb, const float* __restrict__ rfb,
    float* __restrict__ both)
{
    __shared__ alignas(16) float As[16][68];
    __shared__ alignas(16) float Bs[16][68];
    const int hand = blockIdx.z;
    const float* A = hand ? hpR : hpL;        // 512 x 304
    const float* B = hand ? rfw : lfw;        // 300 x 304
    const float* bias = hand ? rfb : lfb;
    const int t = threadIdx.x;
    const int bm = blockIdx.x * 64, bn = blockIdx.y * 64;
    const int lr = t >> 2, kq = (t & 3) * 4;
    const int ty = t >> 4, tx = t & 15;
    float acc[4][4] = {};
    float4 a0 = *(const float4*)(A + (size_t)(bm + lr) * 304 + kq);
    float4 b0 = (bn + lr < 300)
        ? *(const float4*)(B + (size_t)(bn + lr) * 304 + kq)
        : make_float4(0.f, 0.f, 0.f, 0.f);
    for (int ks = 0; ks < 19; ++ks) {
        __syncthreads();
        As[kq + 0][lr] = a0.x; As[kq + 1][lr] = a0.y;
        As[kq + 2][lr] = a0.z; As[kq + 3][lr] = a0.w;
        Bs[kq + 0][lr] = b0.x; Bs[kq + 1][lr] = b0.y;
        Bs[kq + 2][lr] = b0.z; Bs[kq + 3][lr] = b0.w;
        __syncthreads();
        if (ks < 18) {
            int kb = (ks + 1) * 16 + kq;
            a0 = *(const float4*)(A + (size_t)(bm + lr) * 304 + kb);
            b0 = (bn + lr < 300)
                ? *(const float4*)(B + (size_t)(bn + lr) * 304 + kb)
                : make_float4(0.f, 0.f, 0.f, 0.f);
        }
#pragma unroll
        for (int k = 0; k < 16; ++k) {
            float4 av = *(const float4*)&As[k][ty * 4];
            float4 bv = *(const float4*)&Bs[k][tx * 4];
            float aa[4] = {av.x, av.y, av.z, av.w};
            float bb[4] = {bv.x, bv.y, bv.z, bv.w};
#pragma unroll
            for (int i = 0; i < 4; ++i)
#pragma unroll
                for (int j = 0; j < 4; ++j)
                    acc[i][j] = fmaf(aa[i], bb[j], acc[i][j]);
        }
    }
#pragma unroll
    for (int i = 0; i < 4; ++i) {
        int m = bm + ty * 4 + i;
#pragma unroll
        for (int j = 0; j < 4; ++j) {
            int n = bn + tx * 4 + j;
            if (n < 300)
                both[(size_t)m * 600 + hand * 300 + n] =
                    fmaxf(acc[i][j] + bias[n], 0.f);
        }
    }
}

// squaring partial: Psum[z] = P[:, chunk] @ P[chunk, :]  (plain AB)
__global__ __launch_bounds__(256) void sq_gemm(
    const float* __restrict__ P, float* __restrict__ Psum)
{
    __shared__ alignas(16) float As[16][68];
    __shared__ alignas(16) float Bs[16][68];
    const int t = threadIdx.x;
    const int bm = blockIdx.x * 64, bn = blockIdx.y * 64, z = blockIdx.z;
    const int k0 = z * 128;
    const int kend = (k0 + 128 < 500) ? k0 + 128 : 500;
    const int lr = t >> 2, kq = (t & 3) * 4;
    const int kr = t >> 4, cq = (t & 15) * 4;
    const int ty = t >> 4, tx = t & 15;
    float acc[4][4] = {};
    float4 a0 = ldg4_guard(P, bm + lr, 500, k0 + kq, kend, 500);
    float4 b0 = ldg4_guard(P, k0 + kr, kend, bn + cq, 500, 500);
    for (int ks = 0; ks < 8; ++ks) {
        __syncthreads();
        As[kq + 0][lr] = a0.x; As[kq + 1][lr] = a0.y;
        As[kq + 2][lr] = a0.z; As[kq + 3][lr] = a0.w;
        *(float4*)&Bs[kr][cq] = b0;
        __syncthreads();
        if (ks < 7) {
            a0 = ldg4_guard(P, bm + lr, 500, k0 + (ks + 1) * 16 + kq, kend, 500);
            b0 = ldg4_guard(P, k0 + (ks + 1) * 16 + kr, kend, bn + cq, 500, 500);
        }
#pragma unroll
        for (int k = 0; k < 16; ++k) {
            float4 av = *(const float4*)&As[k][ty * 4];
            float4 bv = *(const float4*)&Bs[k][tx * 4];
            float aa[4] = {av.x, av.y, av.z, av.w};
            float bb[4] = {bv.x, bv.y, bv.z, bv.w};
#pragma unroll
            for (int i = 0; i < 4; ++i)
#pragma unroll
                for (int j = 0; j < 4; ++j)
                    acc[i][j] = fmaf(aa[i], bb[j], acc[i][j]);
        }
    }
    float* Cz = Psum + (size_t)z * 250000;
#pragma unroll
    for (int i = 0; i < 4; ++i) {
        int m = bm + ty * 4 + i;
        if (m >= 500) continue;
#pragma unroll
        for (int j = 0; j < 4; ++j) {
            int n = bn + tx * 4 + j;
            if (n < 500) Cz[(size_t)m * 500 + n] = acc[i][j];
        }
    }
}

// reduce Psum -> Pn, and (independent) unew = u*Pold^T + u
__global__ __launch_bounds__(256) void sq_red(
    const float* __restrict__ Psum, float* __restrict__ Pn,
    const float* __restrict__ u, const float* __restrict__ Pold,
    float* __restrict__ un)
{
    __shared__ float red[4];
    const int x = blockIdx.x, t = threadIdx.x;
    if (x < 977) {
        int idx = x * 256 + t;
        if (idx < 250000)
            Pn[idx] = Psum[idx] + Psum[250000 + idx] +
                      Psum[500000 + idx] + Psum[750000 + idx];
    } else {
        int j = x - 977;
        const float* row = Pold + (size_t)j * 500;
        float s = 0.f;
        for (int a = t; a < 500; a += 256) s += u[a] * row[a];
        for (int off = 32; off; off >>= 1) s += __shfl_down(s, off);
        if ((t & 63) == 0) red[t >> 6] = s;
        __syncthreads();
        if (t == 0) un[j] = red[0] + red[1] + red[2] + red[3] + u[j];
    }
}

// h partial: Hsum[z] = hidden[:, chunk] * P32[:, chunk]^T
__global__ __launch_bounds__(256) void h_gemm(
    const float* __restrict__ A, const float* __restrict__ B,
    float* __restrict__ Hsum)
{
    __shared__ alignas(16) float As[16][68];
    __shared__ alignas(16) float Bs[16][68];
    const int t = threadIdx.x;
    const int bm = blockIdx.x * 64, bn = blockIdx.y * 64, z = blockIdx.z;
    const int k0 = z * 128;
    const int kend = (k0 + 128 < 500) ? k0 + 128 : 500;
    const int lr = t >> 2, kq = (t & 3) * 4;
    const int ty = t >> 4, tx = t & 15;
    float acc[4][4] = {};
    float4 a0 = ldg4_guard(A, bm + lr, 512, k0 + kq, kend, 500);
    float4 b0 = ldg4_guard(B, bn + lr, 500, k0 + kq, kend, 500);
    for (int ks = 0; ks < 8; ++ks) {
        __syncthreads();
        As[kq + 0][lr] = a0.x; As[kq + 1][lr] = a0.y;
        As[kq + 2][lr] = a0.z; As[kq + 3][lr] = a0.w;
        Bs[kq + 0][lr] = b0.x; Bs[kq + 1][lr] = b0.y;
        Bs[kq + 2][lr] = b0.z; Bs[kq + 3][lr] = b0.w;
        __syncthreads();
        if (ks < 7) {
            a0 = ldg4_guard(A, bm + lr, 512, k0 + (ks + 1) * 16 + kq, kend, 500);
            b0 = ldg4_guard(B, bn + lr, 500, k0 + (ks + 1) * 16 + kq, kend, 500);
        }
#pragma unroll
        for (int k = 0; k < 16; ++k) {
            float4 av = *(const float4*)&As[k][ty * 4];
            float4 bv = *(const float4*)&Bs[k][tx * 4];
            float aa[4] = {av.x, av.y, av.z, av.w};
            float bb[4] = {bv.x, bv.y, bv.z, bv.w};
#pragma unroll
            for (int i = 0; i < 4; ++i)
#pragma unroll
                for (int j = 0; j < 4; ++j)
                    acc[i][j] = fmaf(aa[i], bb[j], acc[i][j]);
        }
    }
    float* Cz = Hsum + (size_t)z * 256000;
#pragma unroll
    for (int i = 0; i < 4; ++i) {
        int m = bm + ty * 4 + i;
#pragma unroll
        for (int j = 0; j < 4; ++j) {
            int n = bn + tx * 4 + j;
            if (n < 500) Cz[(size_t)m * 500 + n] = acc[i][j];
        }
    }
}

// ---------------------------------------------------------------------------
// small fused kernels
// ---------------------------------------------------------------------------
__global__ __launch_bounds__(128) void hand_conv(
    const float* __restrict__ hand,
    const float* __restrict__ lcw, const float* __restrict__ lcb,
    const float* __restrict__ rcw, const float* __restrict__ rcb,
    float* __restrict__ hpL, float* __restrict__ hpR)
{
    const int b = blockIdx.x;
    __shared__ float x[84];
    __shared__ float cw[2][64];
    __shared__ float cb[2][16];
    const int t = threadIdx.x;
    if (t < 84) x[t] = hand[(size_t)b * 84 + t];
    if (t < 64) { cw[0][t] = lcw[t]; cw[1][t] = rcw[t]; }
    if (t < 16) { cb[0][t] = lcb[t]; cb[1][t] = rcb[t]; }
    __syncthreads();
    for (int idx = t; idx < 608; idx += 128) {
        int hi = idx / 304, rem = idx % 304;
        int o = rem / 19, p = rem % 19;
        int off = hi * 42;
        const float* w = cw[hi];
        float w00 = w[o * 4], w01 = w[o * 4 + 1], w10 = w[o * 4 + 2], w11 = w[o * 4 + 3];
        float bs = cb[hi][o];
        float c0 = w00 * x[off + 2 * p] + w01 * x[off + 2 * p + 2] +
                   w10 * x[off + 2 * p + 1] + w11 * x[off + 2 * p + 3] + bs;
        float c1 = w00 * x[off + 2 * p + 2] + w01 * x[off + 2 * p + 4] +
                   w10 * x[off + 2 * p + 3] + w11 * x[off + 2 * p + 5] + bs;
        float v = fmaxf(fmaxf(c0, c1), 0.f);
        (hi ? hpR : hpL)[(size_t)b * 304 + rem] = v;
    }
}

// conv2 + relu + maxpool(3) computed directly -> bf16 feat (512 x 9536)
__global__ __launch_bounds__(256) void conv2_feat(
    const float* __restrict__ both, const float* __restrict__ w2g,
    const float* __restrict__ b2g, unsigned short* __restrict__ feat)
{
    const int b = blockIdx.x, t = threadIdx.x;
    __shared__ float s[600];
    __shared__ float w2[128];
    __shared__ float b2[32];
    for (int i = t; i < 600; i += 256) s[i] = both[(size_t)b * 600 + i];
    if (t < 128) w2[t] = w2g[t];
    if (t < 32) b2[t] = b2g[t];
    __syncthreads();
    for (int idx = t; idx < 9536; idx += 256) {
        unsigned short ov = 0;
        if (idx < 9504) {
            int o = idx / 297, p = idx - o * 297;
            float w0 = w2[o * 4], w1 = w2[o * 4 + 1];
            float w2v = w2[o * 4 + 2], w3 = w2[o * 4 + 3], bb = b2[o];
            float m = -1e30f;
#pragma unroll
            for (int q = 0; q < 3; ++q) {
                float c = w0 * s[p + q] + w1 * s[p + q + 1] +
                          w2v * s[300 + p + q] + w3 * s[301 + p + q] + bb;
                m = fmaxf(m, c);
            }
            ov = f2bf(fmaxf(m, 0.f));
        }
        feat[(size_t)b * 9536 + idx] = ov;
    }
}

// l2w (500x9504 f32) -> padded bf16 (512x9536)
__global__ __launch_bounds__(256) void cvt_w(
    const float* __restrict__ W, unsigned short* __restrict__ Wb)
{
    int idx = blockIdx.x * 256 + threadIdx.x;
    int row = idx / 1192;
    int k8 = (idx - row * 1192) * 8;
    if (row >= 512) return;
    us8 o = (us8)0;
    if (row < 500 && k8 < 9504) {
        const float* p = W + (size_t)row * 9504 + k8;
        float4 v0 = *(const float4*)p;
        float4 v1 = *(const float4*)(p + 4);
        o[0] = f2bf(v0.x); o[1] = f2bf(v0.y); o[2] = f2bf(v0.z); o[3] = f2bf(v0.w);
        o[4] = f2bf(v1.x); o[5] = f2bf(v1.y); o[6] = f2bf(v1.z); o[7] = f2bf(v1.w);
    }
    *(us8*)(Wb + (size_t)row * 9536 + k8) = o;
}

// final: i2h = sum_z Cp + l2b; h = sum_z Hsum + u32; out = relu((i2h+h)ow^T+ob)
__global__ __launch_bounds__(256) void out_final(
    const float* __restrict__ Cp, const float* __restrict__ l2b,
    const float* __restrict__ Hsum, const float* __restrict__ u32,
    const float* __restrict__ ow, const float* __restrict__ ob,
    float* __restrict__ out, float* __restrict__ hout)
{
    const int b = blockIdx.x, t = threadIdx.x;
    __shared__ float sj[512];
    __shared__ float red[10][4];
    for (int j = t; j < 500; j += 256) {
        float ih = l2b[j];
#pragma unroll
        for (int zz = 0; zz < 8; ++zz)
            ih += Cp[(size_t)zz * 262144 + (size_t)b * 512 + j];
        float h = u32[j];
#pragma unroll
        for (int zz = 0; zz < 4; ++zz)
            h += Hsum[(size_t)zz * 256000 + (size_t)b * 500 + j];
        hout[(size_t)b * 500 + j] = h;
        sj[j] = ih + h;
    }
    __syncthreads();
    const int w = t >> 6;
    for (int o = 0; o < 10; ++o) {
        float acc = 0.f;
        if (t < 500) acc += sj[t] * ow[o * 500 + t];
        if (t + 256 < 500) acc += sj[t + 256] * ow[o * 500 + t + 256];
        for (int off = 32; off; off >>= 1) acc += __shfl_down(acc, off);
        if ((t & 63) == 0) red[o][w] = acc;
    }
    __syncthreads();
    if (t < 10)
        out[(size_t)b * 10 + t] =
            fmaxf(red[t][0] + red[t][1] + red[t][2] + red[t][3] + ob[t], 0.f);
}

extern "C" void kernel_launch(void* const* d_in, const int* in_sizes, int n_in,
                              void* d_out, int out_size, void* d_ws, size_t ws_size,
                              hipStream_t stream) {
    const float* hand   = (const float*)d_in[0];
    const float* hidden = (const float*)d_in[1];
    const float* lcw = (const float*)d_in[2];
    const float* lcb = (const float*)d_in[3];
    const float* lfw = (const float*)d_in[4];
    const float* lfb = (const float*)d_in[5];
    const float* rcw = (const float*)d_in[6];
    const float* rcb = (const float*)d_in[7];
    const float* rfw = (const float*)d_in[8];
    const float* rfb = (const float*)d_in[9];
    const float* w2  = (const float*)d_in[10];
    const float* b2  = (const float*)d_in[11];
    const float* l2w = (const float*)d_in[12];
    const float* l2b = (const float*)d_in[13];
    const float* hw  = (const float*)d_in[14];
    const float* hb  = (const float*)d_in[15];
    const float* ow  = (const float*)d_in[16];
    const float* ob  = (const float*)d_in[17];

    char* wsb = (char*)d_ws;
    // [0, 8MB): Cp (mfma partials, 8 x 1MB).  Overlaid early by hp/both
    // (dead before mfma_bt writes Cp).
    float* Cp   = (float*)wsb;
    float* hpL  = (float*)wsb;                    // 512*304*4 = 622,592
    float* hpR  = (float*)(wsb + 622592);
    float* both = (float*)(wsb + 1245184);        // 512*600*4 -> ends @2.47MB
    // [8MB, 8MB+19.53MB): featb + wbf (bf16).  After mfma_bt these are dead
    // and overlaid by the squaring-chain buffers.
    char* base1 = wsb + 8388608;
    unsigned short* featb = (unsigned short*)base1;            // 9,764,864 B
    unsigned short* wbf   = (unsigned short*)(base1 + 9764864);// 9,764,864 B
    float* Psum = (float*)base1;                  // 4 x 1,000,000 B
    float* Pa   = (float*)(base1 + 4000000);
    float* Pb   = (float*)(base1 + 5000000);
    float* ua   = (float*)(base1 + 6000000);
    float* ub   = (float*)(base1 + 6002000);
    float* Hsum = (float*)(base1 + 9764864);      // 4 x 1,024,000 B

    float* out  = (float*)d_out;
    float* hout = out + 5120;

    // feature pipeline (frame 31 only)
    cvt_w<<<2384, 256, 0, stream>>>(l2w, wbf);
    hand_conv<<<512, 128, 0, stream>>>(hand + (size_t)31 * 512 * 84,
                                       lcw, lcb, rcw, rcb, hpL, hpR);
    fc_gemm<<<dim3(8, 5, 2), 256, 0, stream>>>(hpL, hpR, lfw, rfw, lfb, rfb, both);
    conv2_feat<<<512, 256, 0, stream>>>(both, w2, b2, featb);
    mfma_bt<<<dim3(8, 8, 8), 256, 0, stream>>>(featb, wbf, Cp, 19, 149);

    // recurrence: 5 squarings
    const float* Pcur = hw;
    const float* ucur = hb;
    float* Pn[5] = {Pa, Pb, Pa, Pb, Pa};
    float* un[5] = {ua, ub, ua, ub, ua};
    for (int i = 0; i < 5; i++) {
        sq_gemm<<<dim3(8, 8, 4), 256, 0, stream>>>(Pcur, Psum);
        sq_red<<<1477, 256, 0, stream>>>(Psum, Pn[i], ucur, Pcur, un[i]);
        Pcur = Pn[i];
        ucur = un[i];
    }
    h_gemm<<<dim3(8, 8, 4), 256, 0, stream>>>(hidden, Pcur, Hsum);
    out_final<<<512, 256, 0, stream>>>(Cp, l2b, Hsum, ucur, ow, ob, out, hout);
}